// Round 1
// baseline (62.934 us; speedup 1.0000x reference)
//
#include <hip/hip_runtime.h>

#define H 144
#define W 144
#define T 10
#define NPIX (H * W)

__device__ __forceinline__ float fast_sigmoid(float z) {
    return 1.0f / (1.0f + __expf(-z));
}

__device__ __forceinline__ float fast_tanh(float z) {
    // tanh(z) = 1 - 2/(exp(2z)+1); accurate to ~1e-6 with __expf, well inside 4.6e-3
    return 1.0f - 2.0f / (__expf(2.0f * z) + 1.0f);
}

__global__ __launch_bounds__(256) void lstm_pixel_kernel(
    const float* __restrict__ x,     // (T, H, W)
    const float* __restrict__ w_ih,  // (4,1)
    const float* __restrict__ w_hh,  // (4,1)
    const float* __restrict__ b_ih,  // (4,)
    const float* __restrict__ b_hh,  // (4,)
    float* __restrict__ out)         // (H*W) — out[h*W+w] = c_final(h,w)
{
    const int idx = blockIdx.x * blockDim.x + threadIdx.x;
    if (idx >= NPIX) return;

    // Scalar gate weights (wave-uniform broadcast loads, cached)
    const float wi0 = w_ih[0], wi1 = w_ih[1], wi2 = w_ih[2], wi3 = w_ih[3];
    const float wh0 = w_hh[0], wh1 = w_hh[1], wh2 = w_hh[2], wh3 = w_hh[3];
    const float b0 = b_ih[0] + b_hh[0];
    const float b1 = b_ih[1] + b_hh[1];
    const float b2 = b_ih[2] + b_hh[2];
    const float b3 = b_ih[3] + b_hh[3];

    // Preload the whole time series (coalesced across lanes; compiler can
    // issue all 10 loads before the serial recurrence starts)
    float xs[T];
#pragma unroll
    for (int t = 0; t < T; ++t) xs[t] = x[t * NPIX + idx];

    float h = 0.0f, c = 0.0f;
#pragma unroll
    for (int t = 0; t < T; ++t) {
        const float xt = xs[t];
        const float zi = fmaf(xt, wi0, fmaf(h, wh0, b0));
        const float zf = fmaf(xt, wi1, fmaf(h, wh1, b1));
        const float zg = fmaf(xt, wi2, fmaf(h, wh2, b2));
        const float zo = fmaf(xt, wi3, fmaf(h, wh3, b3));
        const float ig = fast_sigmoid(zi);
        const float fg = fast_sigmoid(zf);
        const float gg = fast_tanh(zg);
        const float og = fast_sigmoid(zo);
        c = fmaf(fg, c, ig * gg);
        h = og * fast_tanh(c);
    }
    out[idx] = c;
}

extern "C" void kernel_launch(void* const* d_in, const int* in_sizes, int n_in,
                              void* d_out, int out_size, void* d_ws, size_t ws_size,
                              hipStream_t stream) {
    const float* x    = (const float*)d_in[0];
    const float* w_ih = (const float*)d_in[1];
    const float* w_hh = (const float*)d_in[2];
    const float* b_ih = (const float*)d_in[3];
    const float* b_hh = (const float*)d_in[4];
    float* out = (float*)d_out;

    const int threads = 256;
    const int blocks = (NPIX + threads - 1) / threads;  // 81
    lstm_pixel_kernel<<<blocks, threads, 0, stream>>>(x, w_ih, w_hh, b_ih, b_hh, out);
}